// Round 4
// baseline (4766.238 us; speedup 1.0000x reference)
//
#include <hip/hip_runtime.h>
#include <hip/hip_bf16.h>

#define S_ 64
#define B_ 32
#define V_ 32000
#define E_ 512
#define H_ 1024
#define H3_ 3072

typedef __hip_bfloat16 bf16;
typedef __attribute__((ext_vector_type(8))) short s8v;
typedef __attribute__((ext_vector_type(4))) float f4;

__device__ __forceinline__ float b2f(bf16 x){ return __bfloat162float(x); }
__device__ __forceinline__ bf16  f2b(float x){ return __float2bfloat16(x); }
__device__ __forceinline__ float bfu2f(unsigned short u){
  union { unsigned u; float f; } c; c.u = ((unsigned)u) << 16; return c.f;
}
#define MFMA16(a,b,c) __builtin_amdgcn_mfma_f32_16x16x32_bf16((a),(b),(c),0,0,0)

__device__ __forceinline__ float fsigmoid(float x){ return 1.f/(1.f + __expf(-x)); }
__device__ __forceinline__ float ftanh(float x){ float e2 = __expf(2.f*x); return 1.f - 2.f/(e2 + 1.f); }

// ---- device-scope (LLC-coherent) accessors ----
__device__ __forceinline__ unsigned long long dld64(const void* p){
  return __hip_atomic_load((const unsigned long long*)p, __ATOMIC_RELAXED, __HIP_MEMORY_SCOPE_AGENT);
}
__device__ __forceinline__ float dldf(const void* p){
  unsigned u = __hip_atomic_load((const unsigned*)p, __ATOMIC_RELAXED, __HIP_MEMORY_SCOPE_AGENT);
  union{unsigned u; float f;} c; c.u=u; return c.f;
}
__device__ __forceinline__ void dstf(void* p, float v){
  union{float f; unsigned u;} c; c.f=v;
  __hip_atomic_store((unsigned*)p, c.u, __ATOMIC_RELAXED, __HIP_MEMORY_SCOPE_AGENT);
}
__device__ __forceinline__ void dsth(void* p, bf16 v){
  union{bf16 h; unsigned short u;} c; c.h=v;
  __hip_atomic_store((unsigned short*)p, c.u, __ATOMIC_RELAXED, __HIP_MEMORY_SCOPE_AGENT);
}
__device__ __forceinline__ unsigned dldu(const unsigned* p){
  return __hip_atomic_load(p, __ATOMIC_RELAXED, __HIP_MEMORY_SCOPE_AGENT);
}
__device__ __forceinline__ void dstu(unsigned* p, unsigned v){
  __hip_atomic_store(p, v, __ATOMIC_RELAXED, __HIP_MEMORY_SCOPE_AGENT);
}

// ---- epoch/flag grid barrier: no atomic RMW anywhere ----
// role 0 = master (block 0: scan arr, publish go), 1 = arrive+wait, 2 = wait-only
template<int NARR>
__device__ __forceinline__ void gsync(unsigned* arr, unsigned* go, unsigned ep, int bid, int role){
  __syncthreads();               // drains per-wave vmcnt: block's device stores LLC-visible
  if (role == 0){
    if (threadIdx.x < 64){
      for(;;){
        bool ok = true;
        if (threadIdx.x > 0 && threadIdx.x < NARR) ok = (dldu(arr + threadIdx.x) >= ep);
        if (NARR > 64){
          int i2 = threadIdx.x + 64;
          if (i2 < NARR) ok = ok && (dldu(arr + i2) >= ep);
        }
        if (__all(ok)) break;
        __builtin_amdgcn_s_sleep(1);
      }
      if (threadIdx.x == 0) dstu(go, ep);
    }
  } else if (threadIdx.x == 0){
    if (role == 1) dstu(arr + bid, ep);
    while (dldu(go) < ep) __builtin_amdgcn_s_sleep(1);
  }
  __syncthreads();
  asm volatile("" ::: "memory");
}

// ---- prep kernels (vectorized: 8 elems / thread) ----
__global__ __launch_bounds__(256) void cast_bf16_k(const float* __restrict__ s, bf16* __restrict__ d, int n8){
  int stride = gridDim.x*256;
  for (int i = blockIdx.x*256 + threadIdx.x; i < n8; i += stride){
    f4 a = *((const f4*)s + (size_t)i*2);
    f4 b = *((const f4*)s + (size_t)i*2 + 1);
    union { s8v v; bf16 h[8]; } o;
    #pragma unroll
    for (int k=0;k<4;k++){ o.h[k]=f2b(a[k]); o.h[4+k]=f2b(b[k]); }
    *((s8v*)d + i) = o.v;
  }
}
__global__ __launch_bounds__(256) void gather_x_k(const float* __restrict__ emb, const int* __restrict__ seq, bf16* __restrict__ d){
  int i = blockIdx.x*256 + threadIdx.x;     // [0, 2048*64)
  int row = i >> 6, e8 = i & 63;
  const float* src = emb + (size_t)seq[row]*E_;
  f4 a = *((const f4*)src + e8*2);
  f4 b = *((const f4*)src + e8*2 + 1);
  union { s8v v; bf16 h[8]; } o;
  #pragma unroll
  for (int k=0;k<4;k++){ o.h[k]=f2b(a[k]); o.h[4+k]=f2b(b[k]); }
  *((s8v*)d + i) = o.v;
}
__global__ __launch_bounds__(256) void gather_lo_k(const float* __restrict__ emb, const int* __restrict__ tseq, const float* __restrict__ o0, bf16* __restrict__ d){
  int i = blockIdx.x*256 + threadIdx.x;     // [0, 2048*64)
  int row = i >> 6, e8 = i & 63;
  int t = row >> 5, b = row & 31;
  const float* src = (t == 0) ? o0 : (emb + (size_t)tseq[(t-1)*B_ + b]*E_);
  f4 a = *((const f4*)src + e8*2);
  f4 c = *((const f4*)src + e8*2 + 1);
  union { s8v v; bf16 h[8]; } o;
  #pragma unroll
  for (int k=0;k<4;k++){ o.h[k]=f2b(a[k]); o.h[4+k]=f2b(c[k]); }
  *((s8v*)d + i) = o.v;
}

// ---- generic bf16 MFMA GEMM: C[M,N] (+= / =) A[M,K] * B[N,K]^T (+bias) ----
template<int WB16, int ACC>
__global__ __launch_bounds__(256) void gemm_bt(const bf16* __restrict__ A, int lda,
                                               const bf16* __restrict__ B, int ldb,
                                               const float* __restrict__ bias,
                                               void* __restrict__ Cp, int ldc, int K)
{
  __shared__ bf16 a_sm[128][40];
  __shared__ bf16 b_sm[128][40];
  const int tid = threadIdx.x;
  const int m0 = blockIdx.y*128, n0 = blockIdx.x*128;
  const int w = tid>>6, l = tid&63;
  const int wm = w>>1, wn = w&1;
  f4 acc[4][4];
  #pragma unroll
  for (int i=0;i<4;i++)
    #pragma unroll
    for (int j=0;j<4;j++) acc[i][j] = (f4){0.f,0.f,0.f,0.f};
  const int srow = tid>>1, skc = (tid&1)*16;
  const int ar = l&15, koff = (l>>4)*8;
  for (int k0 = 0; k0 < K; k0 += 32){
    __syncthreads();
    const s8v* pa = (const s8v*)(A + (size_t)(m0+srow)*lda + k0 + skc);
    const s8v* pb = (const s8v*)(B + (size_t)(n0+srow)*ldb + k0 + skc);
    *(s8v*)&a_sm[srow][skc]   = pa[0];
    *(s8v*)&a_sm[srow][skc+8] = pa[1];
    *(s8v*)&b_sm[srow][skc]   = pb[0];
    *(s8v*)&b_sm[srow][skc+8] = pb[1];
    __syncthreads();
    s8v av[4], bv[4];
    #pragma unroll
    for (int i=0;i<4;i++) av[i] = *(const s8v*)&a_sm[wm*64 + i*16 + ar][koff];
    #pragma unroll
    for (int j=0;j<4;j++) bv[j] = *(const s8v*)&b_sm[wn*64 + j*16 + ar][koff];
    #pragma unroll
    for (int i=0;i<4;i++)
      #pragma unroll
      for (int j=0;j<4;j++)
        acc[i][j] = MFMA16(av[i], bv[j], acc[i][j]);
  }
  const int rb = (l>>4)*4;
  #pragma unroll
  for (int i=0;i<4;i++){
    #pragma unroll
    for (int j=0;j<4;j++){
      int col = n0 + wn*64 + j*16 + ar;
      float badd = bias ? bias[col] : 0.f;
      #pragma unroll
      for (int r=0;r<4;r++){
        int row = m0 + wm*64 + i*16 + rb + r;
        size_t idx = (size_t)row*ldc + col;
        float v = acc[i][j][r] + badd;
        if (ACC) v += ((const float*)Cp)[idx];
        if (WB16) ((bf16*)Cp)[idx] = f2b(v);
        else      ((float*)Cp)[idx] = v;
      }
    }
  }
}

// ---- bidirectional encoder GRU: 64 blocks x 4 waves, 1 sync/step ----
__global__ __launch_bounds__(256) void enc_loop_k(
  const float* __restrict__ gi_f, const float* __restrict__ gi_b,
  const bf16* __restrict__ whhf, const bf16* __restrict__ whhb,
  const float* __restrict__ bhhf, const float* __restrict__ bhhb,
  const float* __restrict__ enc_init,
  bf16* __restrict__ hb, bf16* __restrict__ enc_out,
  unsigned* __restrict__ arr, unsigned* __restrict__ go)
{
  __shared__ bf16 hst[16][1032];
  const int tid = threadIdx.x, bid = blockIdx.x;
  const int w = tid>>6, l = tid&63;
  const int lr = l&15, koff = (l>>4)*8, rb = (l>>4)*4;
  const int dir = bid>>5;
  const int mt  = (bid&31)>>4;
  const int jt  = ((bid&31)*4 + w) & 63;
  const int col = jt*16 + lr;
  const bf16* W    = dir ? whhb : whhf;
  const float* gi  = dir ? gi_b : gi_f;
  const float* bhh = dir ? bhhb : bhhf;
  const float br_ = bhh[col], bz_ = bhh[H_+col], bn_ = bhh[2*H_+col];
  const bf16* pr = W + (size_t)(jt*16 + lr)*H_ + koff;
  const bf16* pz = pr + (size_t)H_*H_;
  const bf16* pn = pz + (size_t)H_*H_;
  const int role = (bid==0) ? 0 : 1;
  float hreg[4];
  {
    float v = enc_init[dir*H_ + col];
    bf16 vb = f2b(v);
    #pragma unroll
    for (int ri=0; ri<4; ++ri){
      hreg[ri] = v;
      dsth(hb + dir*32768 + (mt*16 + rb + ri)*H_ + col, vb);  // buf 0
    }
  }
  gsync<64>(arr, go, 1u, bid, role);
  for (int s = 0; s < 64; ++s){
    const int rbuf = s&1, wbuf = rbuf^1;
    // stage my 16 h rows -> LDS
    {
      const bf16* src = hb + rbuf*65536 + dir*32768 + mt*16*H_;
      #pragma unroll
      for (int c = 0; c < 16; ++c){
        int g = c*256 + tid;                 // 4096 chunks of 8B
        *(unsigned long long*)&hst[g>>8][(g&255)*4] = dld64(src + g*4);
      }
    }
    __syncthreads();
    f4 accr = (f4){0,0,0,0}, accz = (f4){0,0,0,0}, accn = (f4){0,0,0,0};
    #pragma unroll 4
    for (int k0 = 0; k0 < H_; k0 += 32){
      s8v a = *(const s8v*)&hst[lr][koff + k0];
      accr = MFMA16(a, *(const s8v*)(pr + k0), accr);
      accz = MFMA16(a, *(const s8v*)(pz + k0), accz);
      accn = MFMA16(a, *(const s8v*)(pn + k0), accn);
    }
    const int es = dir ? (63 - s) : s;
    bf16* hbw = hb + wbuf*65536 + dir*32768;
    #pragma unroll
    for (int ri = 0; ri < 4; ++ri){
      const int b_ = mt*16 + rb + ri;
      const size_t gr = (size_t)(es*B_ + b_)*H3_;
      float ir = gi[gr + col], iz = gi[gr + H_ + col], inn = gi[gr + 2*H_ + col];
      float rg = fsigmoid(ir + accr[ri] + br_);
      float zg = fsigmoid(iz + accz[ri] + bz_);
      float ng = ftanh(inn + rg*(accn[ri] + bn_));
      float hnew = (1.f - zg)*ng + zg*hreg[ri];
      hreg[ri] = hnew;
      bf16 h16 = f2b(hnew);
      dsth(hbw + b_*H_ + col, h16);
      enc_out[(size_t)(es*B_ + b_)*2048 + dir*H_ + col] = h16;
    }
    gsync<64>(arr, go, (unsigned)(s+2), bid, role);
  }
}

// ---- decoder with attention: 128 blocks ----
// roles: P (0..15): hW1 producer; G (16..63): gh producer (skips sync1); B (64..127): attention
__global__ __launch_bounds__(256) void dec_loop_k(
  const float* __restrict__ gi_base,   // [2048][3072]
  const bf16* __restrict__ encW1b,     // [2048][1024]
  const bf16* __restrict__ encWgb,     // [2048][3072]
  const bf16* __restrict__ whhd,       // [3072][1024]
  const float* __restrict__ bhhd,
  const bf16* __restrict__ w1b,        // [1024][3072]
  const float* __restrict__ attnW2,    // [1024]
  const float* __restrict__ dinh,      // [1024]
  bf16* __restrict__ hdb,              // [32][1024] device-scope
  bf16* __restrict__ hW1b,             // [32][1024] device-scope
  float* __restrict__ gh,              // [32][3072] device-scope
  float* __restrict__ wat_t,           // [32][64]   device-scope (transposed)
  bf16* __restrict__ h_all,            // [2048][1024] normal
  unsigned* __restrict__ arr, unsigned* __restrict__ go)
{
  __shared__ bf16 hst[16][1032];
  __shared__ float watst[64];
  __shared__ float sc[32];
  const int tid = threadIdx.x, bid = blockIdx.x;
  const int w = tid>>6, l = tid&63;
  const int lr = l&15, koff = (l>>4)*8, rbv = (l>>4)*4;
  const int tg = bid*256 + tid;
  const int db = tg>>10, dj = tg&1023;
  const bool isP = (bid < 16), isG = (bid >= 16 && bid < 64), isB = (bid >= 64);
  const int role = (bid==0) ? 0 : 1;
  float hreg = dinh[dj];
  dsth(hdb + tg, f2b(hreg));

  // B: hoist loop-invariant encW1 fragments into registers
  int sB = bid - 64;
  const int b_ = tid>>3, part = tid&7;
  s8v evv[16];
  if (isB){
    const bf16* e = encW1b + (size_t)(sB*B_ + b_)*H_ + part*128;
    #pragma unroll
    for (int ii=0; ii<16; ++ii) evv[ii] = *(const s8v*)(e + ii*8);
  }
  gsync<128>(arr, go, 1u, bid, role);

  for (int t = 0; t < 64; ++t){
    const unsigned ep1 = 3u*t + 2u, ep2 = 3u*t + 3u, ep3 = 3u*t + 4u;
    // ---- P: stage h rows, compute hW1 (2 jt tiles per wave), sync1
    if (isP){
      const int pmt = bid>>3;
      {
        const bf16* src = hdb + pmt*16*H_;
        #pragma unroll
        for (int c = 0; c < 16; ++c){
          int g = c*256 + tid;
          *(unsigned long long*)&hst[g>>8][(g&255)*4] = dld64(src + g*4);
        }
      }
      __syncthreads();
      const int pjt0 = ((bid&7)*4 + w)*2;
      const bf16* pb0 = w1b + (size_t)(pjt0*16 + lr)*H3_ + 2048 + koff;
      const bf16* pb1 = pb0 + (size_t)16*H3_;
      f4 a0 = (f4){0,0,0,0}, a1 = (f4){0,0,0,0};
      #pragma unroll 4
      for (int k0 = 0; k0 < H_; k0 += 32){
        s8v a = *(const s8v*)&hst[lr][koff + k0];
        a0 = MFMA16(a, *(const s8v*)(pb0 + k0), a0);
        a1 = MFMA16(a, *(const s8v*)(pb1 + k0), a1);
      }
      #pragma unroll
      for (int ri=0; ri<4; ++ri){
        const int row = pmt*16 + rbv + ri;
        dsth(hW1b + row*H_ + pjt0*16 + lr,      f2b(a0[ri]));
        dsth(hW1b + row*H_ + (pjt0+1)*16 + lr,  f2b(a1[ri]));
      }
      gsync<16>(arr, go, ep1, bid, role);
    } else if (isB){
      gsync<16>(arr, go, ep1, bid, 2);       // wait-only
    }
    // ---- G: gh = h @ Whh^T + bhh (2 nt tiles per wave), concurrent with B
    if (isG){
      const int gmt = (bid < 40) ? 0 : 1;
      {
        const bf16* src = hdb + gmt*16*H_;
        #pragma unroll
        for (int c = 0; c < 16; ++c){
          int g = c*256 + tid;
          *(unsigned long long*)&hst[g>>8][(g&255)*4] = dld64(src + g*4);
        }
      }
      __syncthreads();
      const int gq = (bid - (gmt ? 40 : 16))*4 + w;   // 0..95
      const int gnt0 = gq*2;
      const bf16* pb0 = whhd + (size_t)(gnt0*16 + lr)*H_ + koff;
      const bf16* pb1 = pb0 + (size_t)16*H_;
      const float bv0 = bhhd[gnt0*16 + lr], bv1 = bhhd[(gnt0+1)*16 + lr];
      f4 a0 = (f4){0,0,0,0}, a1 = (f4){0,0,0,0};
      #pragma unroll 4
      for (int k0 = 0; k0 < H_; k0 += 32){
        s8v a = *(const s8v*)&hst[lr][koff + k0];
        a0 = MFMA16(a, *(const s8v*)(pb0 + k0), a0);
        a1 = MFMA16(a, *(const s8v*)(pb1 + k0), a1);
      }
      #pragma unroll
      for (int ri=0; ri<4; ++ri){
        const int row = gmt*16 + rbv + ri;
        dstf(gh + row*H3_ + gnt0*16 + lr,     a0[ri] + bv0);
        dstf(gh + row*H3_ + (gnt0+1)*16 + lr, a1[ri] + bv1);
      }
    }
    // ---- B: scores + softmax over batch
    if (isB){
      unsigned long long hvv[32];
      const bf16* hwp = hW1b + b_*H_ + part*128;
      #pragma unroll
      for (int q=0; q<32; ++q) hvv[q] = dld64(hwp + q*4);
      const float* w2p = attnW2 + part*128;
      float p = 0.f;
      #pragma unroll 2
      for (int ii=0; ii<16; ++ii){
        union { unsigned long long u2[2]; unsigned short uu[8]; } hv;
        hv.u2[0] = hvv[2*ii]; hv.u2[1] = hvv[2*ii+1];
        union { s8v v; unsigned short uu[8]; } ev;
        ev.v = evv[ii];
        f4 wa  = *(const f4*)(w2p + ii*8);
        f4 wb2 = *(const f4*)(w2p + ii*8 + 4);
        #pragma unroll
        for (int k=0;k<8;k++){
          float x = bfu2f(ev.uu[k]) + bfu2f(hv.uu[k]);
          p += (k<4 ? wa[k] : wb2[k-4])*ftanh(x);
        }
      }
      p += __shfl_xor(p,1); p += __shfl_xor(p,2); p += __shfl_xor(p,4);
      if (part == 0) sc[b_] = p;
      __syncthreads();
      if (tid < 32){
        float evx = __expf(sc[tid]);
        float ssum = evx;
        ssum += __shfl_xor(ssum,1);  ssum += __shfl_xor(ssum,2);
        ssum += __shfl_xor(ssum,4);  ssum += __shfl_xor(ssum,8);
        ssum += __shfl_xor(ssum,16);
        dstf(wat_t + tid*64 + sB, evx/ssum);
      }
    }
    gsync<128>(arr, go, ep2, bid, role);
    // ---- phase D: glimpse weighted sum + GRU pointwise
    if (tid < 64) watst[tid] = dldf(wat_t + db*64 + tid);
    float hr_ = dldf(gh + db*H3_ + dj);
    float hz_ = dldf(gh + db*H3_ + H_ + dj);
    float hn_ = dldf(gh + db*H3_ + 2*H_ + dj);
    __syncthreads();
    {
      float g0=0.f, g1=0.f, g2=0.f;
      #pragma unroll 4
      for (int s2=0;s2<64;++s2){
        float wv = watst[s2];
        const bf16* ro = encWgb + (size_t)(s2*B_ + db)*H3_ + dj;
        g0 += wv*b2f(ro[0]);
        g1 += wv*b2f(ro[H_]);
        g2 += wv*b2f(ro[2*H_]);
      }
      const size_t gr = (size_t)(t*B_ + db)*H3_;
      float ir  = gi_base[gr + dj] + g0;
      float iz  = gi_base[gr + H_ + dj] + g1;
      float inn = gi_base[gr + 2*H_ + dj] + g2;
      float rg = fsigmoid(ir + hr_);
      float zg = fsigmoid(iz + hz_);
      float ng = ftanh(inn + rg*hn_);
      float hnew = (1.f - zg)*ng + zg*hreg;
      hreg = hnew;
      bf16 h16 = f2b(hnew);
      dsth(hdb + db*H_ + dj, h16);
      h_all[(size_t)(t*B_ + db)*H_ + dj] = h16;
    }
    gsync<128>(arr, go, ep3, bid, role);
  }
}

// ---- 2-pass online row softmax over V (in place on d_out) ----
__global__ __launch_bounds__(256) void softmax_rows_k(float* __restrict__ out){
  __shared__ float wm[4], wl[4];
  const int tid = threadIdx.x;
  float* p = out + (size_t)blockIdx.x*V_;
  float m = -1e30f, lsum = 0.f;
  for (int j = tid; j < V_; j += 256){
    float v = p[j];
    float mn = fmaxf(m, v);
    lsum = lsum*__expf(m - mn) + __expf(v - mn);
    m = mn;
  }
  #pragma unroll
  for (int o = 32; o; o >>= 1){
    float mo = __shfl_xor(m, o), lo_ = __shfl_xor(lsum, o);
    float mn = fmaxf(m, mo);
    lsum = lsum*__expf(m - mn) + lo_*__expf(mo - mn);
    m = mn;
  }
  if ((tid&63)==0){ wm[tid>>6] = m; wl[tid>>6] = lsum; }
  __syncthreads();
  float M = fmaxf(fmaxf(wm[0],wm[1]), fmaxf(wm[2],wm[3]));
  float L = wl[0]*__expf(wm[0]-M) + wl[1]*__expf(wm[1]-M)
          + wl[2]*__expf(wm[2]-M) + wl[3]*__expf(wm[3]-M);
  float inv = 1.f/L;
  for (int j = tid; j < V_; j += 256) p[j] = __expf(p[j]-M)*inv;
}

extern "C" void kernel_launch(void* const* d_in, const int* in_sizes, int n_in,
                              void* d_out, int out_size, void* d_ws, size_t ws_size,
                              hipStream_t stream)
{
  (void)in_sizes; (void)n_in; (void)out_size; (void)ws_size;
  const int*   iseq  = (const int*)d_in[0];
  const int*   tseq  = (const int*)d_in[1];
  const float* emb   = (const float*)d_in[2];
  const float* wihf  = (const float*)d_in[3];
  const float* whhf_f= (const float*)d_in[4];
  const float* bihf  = (const float*)d_in[5];
  const float* bhhf  = (const float*)d_in[6];
  const float* wihb  = (const float*)d_in[7];
  const float* whhb_f= (const float*)d_in[8];
  const float* bihb  = (const float*)d_in[9];
  const float* bhhb  = (const float*)d_in[10];
  const float* einit = (const float*)d_in[11];
  const float* wihd  = (const float*)d_in[12];
  const float* whhd_f= (const float*)d_in[13];
  const float* bihd  = (const float*)d_in[14];
  const float* bhhd  = (const float*)d_in[15];
  const float* dinh  = (const float*)d_in[16];
  const float* dino  = (const float*)d_in[17];
  const float* w1    = (const float*)d_in[18];
  const float* w2    = (const float*)d_in[19];
  const float* outw  = (const float*)d_in[20];
  const float* outb  = (const float*)d_in[21];
  float* out = (float*)d_out;

  char* ws = (char*)d_ws;
  size_t off = 0;
  auto alloc = [&](size_t bytes)->char*{ char* p = ws + off; off += (bytes + 255) & ~(size_t)255; return p; };
  unsigned* bar  = (unsigned*)alloc(2048);
  unsigned* enc_arr = bar;            // 64 slots
  unsigned* enc_go  = bar + 96;
  unsigned* dec_arr = bar + 128;      // 128 slots
  unsigned* dec_go  = bar + 272;
  bf16* x_b      = (bf16*)alloc((size_t)2048*512*2);
  bf16* lo_b     = (bf16*)alloc((size_t)2048*512*2);
  bf16* wihf_b   = (bf16*)alloc((size_t)3072*512*2);
  bf16* wihb_b   = (bf16*)alloc((size_t)3072*512*2);
  bf16* whhf_b   = (bf16*)alloc((size_t)3072*1024*2);
  bf16* whhb_b   = (bf16*)alloc((size_t)3072*1024*2);
  bf16* wihd_b   = (bf16*)alloc((size_t)3072*3072*2);
  bf16* whhd_b   = (bf16*)alloc((size_t)3072*1024*2);
  bf16* w1_b     = (bf16*)alloc((size_t)1024*3072*2);
  bf16* outw_b   = (bf16*)alloc((size_t)32000*1024*2);
  float* gi_f    = (float*)alloc((size_t)2048*3072*4);
  float* gi_b    = (float*)alloc((size_t)2048*3072*4);
  float* gi_d    = (float*)alloc((size_t)2048*3072*4);
  bf16* enc_b    = (bf16*)alloc((size_t)2048*2048*2);
  bf16* encW1_b  = (bf16*)alloc((size_t)2048*1024*2);
  bf16* encWg_b  = (bf16*)alloc((size_t)2048*3072*2);
  bf16*  henc_b  = (bf16*)alloc((size_t)2*65536*2);
  bf16*  hdb     = (bf16*)alloc((size_t)32768*2);
  bf16*  hW1b    = (bf16*)alloc((size_t)32768*2);
  float* ghb     = (float*)alloc((size_t)32*3072*4);
  float* wat_t   = (float*)alloc((size_t)32*64*4);
  bf16*  hall_b  = (bf16*)alloc((size_t)2048*1024*2);

  hipMemsetAsync(bar, 0, 2048, stream);

  auto cgrid = [](int n8){ int g = (n8 + 255)/256; return g > 2048 ? 2048 : g; };
  gather_x_k <<<512, 256, 0, stream>>>(emb, iseq, x_b);
  gather_lo_k<<<512, 256, 0, stream>>>(emb, tseq, dino, lo_b);
  cast_bf16_k<<<cgrid(196608),  256, 0, stream>>>(wihf,   wihf_b, 196608);
  cast_bf16_k<<<cgrid(196608),  256, 0, stream>>>(wihb,   wihb_b, 196608);
  cast_bf16_k<<<cgrid(393216),  256, 0, stream>>>(whhf_f, whhf_b, 393216);
  cast_bf16_k<<<cgrid(393216),  256, 0, stream>>>(whhb_f, whhb_b, 393216);
  cast_bf16_k<<<cgrid(1179648), 256, 0, stream>>>(wihd,   wihd_b, 1179648);
  cast_bf16_k<<<cgrid(393216),  256, 0, stream>>>(whhd_f, whhd_b, 393216);
  cast_bf16_k<<<cgrid(393216),  256, 0, stream>>>(w1,     w1_b,   393216);
  cast_bf16_k<<<cgrid(4096000), 256, 0, stream>>>(outw,   outw_b, 4096000);

  // batched gi precomputes
  gemm_bt<0,0><<<dim3(24,16), 256, 0, stream>>>(x_b, 512, wihf_b,      512,  bihf,    gi_f, 3072, 512);
  gemm_bt<0,0><<<dim3(24,16), 256, 0, stream>>>(x_b, 512, wihb_b,      512,  bihb,    gi_b, 3072, 512);
  gemm_bt<0,0><<<dim3(24,16), 256, 0, stream>>>(x_b, 512, wihd_b,      3072, bihd,    gi_d, 3072, 512);
  gemm_bt<0,1><<<dim3(24,16), 256, 0, stream>>>(lo_b,512, wihd_b+2560, 3072, nullptr, gi_d, 3072, 512);

  enc_loop_k<<<64, 256, 0, stream>>>(gi_f, gi_b, whhf_b, whhb_b, bhhf, bhhb, einit,
                                     henc_b, enc_b, enc_arr, enc_go);

  // loop-invariant attention precomputes
  gemm_bt<1,0><<<dim3(8,16),  256, 0, stream>>>(enc_b, 2048, w1_b,       3072, nullptr, encW1_b, 1024, 2048);
  gemm_bt<1,0><<<dim3(24,16), 256, 0, stream>>>(enc_b, 2048, wihd_b+512, 3072, nullptr, encWg_b, 3072, 2048);

  dec_loop_k<<<128, 256, 0, stream>>>(gi_d, encW1_b, encWg_b, whhd_b, bhhd, w1_b, w2, dinh,
                                      hdb, hW1b, ghb, wat_t, hall_b, dec_arr, dec_go);

  // batched output projection + softmax
  gemm_bt<0,0><<<dim3(250,16), 256, 0, stream>>>(hall_b, 1024, outw_b, 1024, outb, out, 32000, 1024);
  softmax_rows_k<<<2048, 256, 0, stream>>>(out);
}

// Round 5
// 4389.239 us; speedup vs baseline: 1.0859x; 1.0859x over previous
//
#include <hip/hip_runtime.h>
#include <hip/hip_bf16.h>

#define S_ 64
#define B_ 32
#define V_ 32000
#define E_ 512
#define H_ 1024
#define H3_ 3072

typedef __hip_bfloat16 bf16;
typedef __attribute__((ext_vector_type(8))) short s8v;
typedef __attribute__((ext_vector_type(4))) float f4;
typedef unsigned long long ull;

__device__ __forceinline__ float b2f(bf16 x){ return __bfloat162float(x); }
__device__ __forceinline__ bf16  f2b(float x){ return __float2bfloat16(x); }
__device__ __forceinline__ float bfu2f(unsigned short u){
  union { unsigned u; float f; } c; c.u = ((unsigned)u) << 16; return c.f;
}
#define MFMA16(a,b,c) __builtin_amdgcn_mfma_f32_16x16x32_bf16((a),(b),(c),0,0,0)

__device__ __forceinline__ float fsigmoid(float x){ return 1.f/(1.f + __expf(-x)); }
__device__ __forceinline__ float ftanh(float x){ float e2 = __expf(2.f*x); return 1.f - 2.f/(e2 + 1.f); }

// ---- device-scope (LLC-coherent) accessors: ALWAYS >=8B granularity ----
__device__ __forceinline__ ull dld64(const void* p){
  return __hip_atomic_load((const ull*)p, __ATOMIC_RELAXED, __HIP_MEMORY_SCOPE_AGENT);
}
__device__ __forceinline__ void dst64(void* p, ull v){
  __hip_atomic_store((ull*)p, v, __ATOMIC_RELAXED, __HIP_MEMORY_SCOPE_AGENT);
}
__device__ __forceinline__ float dldf(const void* p){
  unsigned u = __hip_atomic_load((const unsigned*)p, __ATOMIC_RELAXED, __HIP_MEMORY_SCOPE_AGENT);
  union{unsigned u; float f;} c; c.u=u; return c.f;
}
__device__ __forceinline__ unsigned dldu(const unsigned* p){
  return __hip_atomic_load(p, __ATOMIC_RELAXED, __HIP_MEMORY_SCOPE_AGENT);
}
__device__ __forceinline__ void dstu(unsigned* p, unsigned v){
  __hip_atomic_store(p, v, __ATOMIC_RELAXED, __HIP_MEMORY_SCOPE_AGENT);
}

// ---- epoch/flag full barrier: block0 master scans arrivals, publishes go ----
template<int NARR>
__device__ __forceinline__ void gfull(unsigned* arr, unsigned* go, unsigned ep, int bid){
  __syncthreads();
  if (bid == 0){
    if (threadIdx.x < 64){
      const int i1 = threadIdx.x;
      const int i2 = threadIdx.x + 64;
      for(;;){
        bool ok = true;
        if (i1 > 0 && i1 < NARR) ok = (dldu(arr + i1) >= ep);
        if (NARR > 64 && i2 < NARR) ok = ok && (dldu(arr + i2) >= ep);
        if (__all(ok)) break;
        __builtin_amdgcn_s_sleep(1);
      }
      if (threadIdx.x == 0) dstu(go, ep);
    }
  } else if (threadIdx.x == 0){
    dstu(arr + bid, ep);
    while (dldu(go) < ep) __builtin_amdgcn_s_sleep(1);
  }
  __syncthreads();
  asm volatile("" ::: "memory");
}

// ---- prep kernels ----
__global__ __launch_bounds__(256) void cast_bf16_k(const float* __restrict__ s, bf16* __restrict__ d, int n8){
  int stride = gridDim.x*256;
  for (int i = blockIdx.x*256 + threadIdx.x; i < n8; i += stride){
    f4 a = *((const f4*)s + (size_t)i*2);
    f4 b = *((const f4*)s + (size_t)i*2 + 1);
    union { s8v v; bf16 h[8]; } o;
    #pragma unroll
    for (int k=0;k<4;k++){ o.h[k]=f2b(a[k]); o.h[4+k]=f2b(b[k]); }
    *((s8v*)d + i) = o.v;
  }
}
__global__ __launch_bounds__(256) void gather_x_k(const float* __restrict__ emb, const int* __restrict__ seq, bf16* __restrict__ d){
  int i = blockIdx.x*256 + threadIdx.x;
  int row = i >> 6, e8 = i & 63;
  const float* src = emb + (size_t)seq[row]*E_;
  f4 a = *((const f4*)src + e8*2);
  f4 b = *((const f4*)src + e8*2 + 1);
  union { s8v v; bf16 h[8]; } o;
  #pragma unroll
  for (int k=0;k<4;k++){ o.h[k]=f2b(a[k]); o.h[4+k]=f2b(b[k]); }
  *((s8v*)d + i) = o.v;
}
__global__ __launch_bounds__(256) void gather_lo_k(const float* __restrict__ emb, const int* __restrict__ tseq, const float* __restrict__ o0, bf16* __restrict__ d){
  int i = blockIdx.x*256 + threadIdx.x;
  int row = i >> 6, e8 = i & 63;
  int t = row >> 5, b = row & 31;
  const float* src = (t == 0) ? o0 : (emb + (size_t)tseq[(t-1)*B_ + b]*E_);
  f4 a = *((const f4*)src + e8*2);
  f4 c = *((const f4*)src + e8*2 + 1);
  union { s8v v; bf16 h[8]; } o;
  #pragma unroll
  for (int k=0;k<4;k++){ o.h[k]=f2b(a[k]); o.h[4+k]=f2b(c[k]); }
  *((s8v*)d + i) = o.v;
}

// ---- generic bf16 MFMA GEMM (unchanged) ----
template<int WB16, int ACC>
__global__ __launch_bounds__(256) void gemm_bt(const bf16* __restrict__ A, int lda,
                                               const bf16* __restrict__ B, int ldb,
                                               const float* __restrict__ bias,
                                               void* __restrict__ Cp, int ldc, int K)
{
  __shared__ bf16 a_sm[128][40];
  __shared__ bf16 b_sm[128][40];
  const int tid = threadIdx.x;
  const int m0 = blockIdx.y*128, n0 = blockIdx.x*128;
  const int w = tid>>6, l = tid&63;
  const int wm = w>>1, wn = w&1;
  f4 acc[4][4];
  #pragma unroll
  for (int i=0;i<4;i++)
    #pragma unroll
    for (int j=0;j<4;j++) acc[i][j] = (f4){0.f,0.f,0.f,0.f};
  const int srow = tid>>1, skc = (tid&1)*16;
  const int ar = l&15, koff = (l>>4)*8;
  for (int k0 = 0; k0 < K; k0 += 32){
    __syncthreads();
    const s8v* pa = (const s8v*)(A + (size_t)(m0+srow)*lda + k0 + skc);
    const s8v* pb = (const s8v*)(B + (size_t)(n0+srow)*ldb + k0 + skc);
    *(s8v*)&a_sm[srow][skc]   = pa[0];
    *(s8v*)&a_sm[srow][skc+8] = pa[1];
    *(s8v*)&b_sm[srow][skc]   = pb[0];
    *(s8v*)&b_sm[srow][skc+8] = pb[1];
    __syncthreads();
    s8v av[4], bv[4];
    #pragma unroll
    for (int i=0;i<4;i++) av[i] = *(const s8v*)&a_sm[wm*64 + i*16 + ar][koff];
    #pragma unroll
    for (int j=0;j<4;j++) bv[j] = *(const s8v*)&b_sm[wn*64 + j*16 + ar][koff];
    #pragma unroll
    for (int i=0;i<4;i++)
      #pragma unroll
      for (int j=0;j<4;j++)
        acc[i][j] = MFMA16(av[i], bv[j], acc[i][j]);
  }
  const int rb = (l>>4)*4;
  #pragma unroll
  for (int i=0;i<4;i++){
    #pragma unroll
    for (int j=0;j<4;j++){
      int col = n0 + wn*64 + j*16 + ar;
      float badd = bias ? bias[col] : 0.f;
      #pragma unroll
      for (int r=0;r<4;r++){
        int row = m0 + wm*64 + i*16 + rb + r;
        size_t idx = (size_t)row*ldc + col;
        float v = acc[i][j][r] + badd;
        if (ACC) v += ((const float*)Cp)[idx];
        if (WB16) ((bf16*)Cp)[idx] = f2b(v);
        else      ((float*)Cp)[idx] = v;
      }
    }
  }
}

// ---- bidirectional encoder GRU: 64 blocks, XCD-local weights, wide stores ----
// map: x=bid&7, dir=x>>2, g3=bid>>3: mt=g3>>2, jtb=(x&3)*16+(g3&3)*4, wave jt=jtb+w
__global__ __launch_bounds__(256) void enc_loop_k(
  const float* __restrict__ gi_f, const float* __restrict__ gi_b,
  const bf16* __restrict__ whhf, const bf16* __restrict__ whhb,
  const float* __restrict__ bhhf, const float* __restrict__ bhhb,
  const float* __restrict__ enc_init,
  bf16* __restrict__ hb, bf16* __restrict__ enc_out,
  unsigned* __restrict__ bar)
{
  __shared__ bf16 hst[16][1032];
  __shared__ bf16 hsT[16][64];
  unsigned* arrE = bar;        // 64
  unsigned* goE  = bar + 80;
  const int tid = threadIdx.x, bid = blockIdx.x;
  const int w = tid>>6, l = tid&63;
  const int lr = l&15, koff = (l>>4)*8, rb = (l>>4)*4;
  const int x = bid&7, g3 = bid>>3;
  const int dir = x>>2;
  const int mt = g3>>2;
  const int jtb = (x&3)*16 + (g3&3)*4;
  const int jt = jtb + w;
  const int col = jt*16 + lr;
  const bf16* W    = dir ? whhb : whhf;
  const float* gi  = dir ? gi_b : gi_f;
  const float* bhh = dir ? bhhb : bhhf;
  const float br_ = bhh[col], bz_ = bhh[H_+col], bn_ = bhh[2*H_+col];
  const bf16* pr = W + (size_t)(jt*16 + lr)*H_ + koff;
  const bf16* pz = pr + (size_t)H_*H_;
  const bf16* pn = pz + (size_t)H_*H_;
  float hreg[4];
  // init h buf0 (wide store via LDS)
  {
    float v = enc_init[dir*H_ + col];
    #pragma unroll
    for (int ri=0; ri<4; ++ri){
      hreg[ri] = v;
      hsT[rb+ri][w*16+lr] = f2b(v);
    }
    __syncthreads();
    const int row = tid>>4, seg = tid&15;
    dst64(hb + dir*32768 + (size_t)(mt*16+row)*H_ + jtb*16 + seg*4, *(ull*)&hsT[row][seg*4]);
  }
  gfull<64>(arrE, goE, 1u, bid);
  for (int s = 0; s < 64; ++s){
    const int rbuf = s&1, wbuf = rbuf^1;
    {
      const bf16* src = hb + rbuf*65536 + dir*32768 + (size_t)mt*16*H_;
      #pragma unroll
      for (int c = 0; c < 16; ++c){
        int g = c*256 + tid;
        *(ull*)&hst[g>>8][(g&255)*4] = dld64(src + g*4);
      }
    }
    __syncthreads();
    f4 accr = (f4){0,0,0,0}, accz = (f4){0,0,0,0}, accn = (f4){0,0,0,0};
    #pragma unroll 4
    for (int k0 = 0; k0 < H_; k0 += 32){
      s8v a = *(const s8v*)&hst[lr][koff + k0];
      accr = MFMA16(a, *(const s8v*)(pr + k0), accr);
      accz = MFMA16(a, *(const s8v*)(pz + k0), accz);
      accn = MFMA16(a, *(const s8v*)(pn + k0), accn);
    }
    const int es = dir ? (63 - s) : s;
    #pragma unroll
    for (int ri = 0; ri < 4; ++ri){
      const int b_ = mt*16 + rb + ri;
      const size_t gr = (size_t)(es*B_ + b_)*H3_;
      float ir = gi[gr + col], iz = gi[gr + H_ + col], inn = gi[gr + 2*H_ + col];
      float rg = fsigmoid(ir + accr[ri] + br_);
      float zg = fsigmoid(iz + accz[ri] + bz_);
      float ng = ftanh(inn + rg*(accn[ri] + bn_));
      float hnew = (1.f - zg)*ng + zg*hreg[ri];
      hreg[ri] = hnew;
      hsT[rb+ri][w*16+lr] = f2b(hnew);
    }
    __syncthreads();
    {
      const int row = tid>>4, seg = tid&15;
      ull v = *(ull*)&hsT[row][seg*4];
      dst64(hb + wbuf*65536 + dir*32768 + (size_t)(mt*16+row)*H_ + jtb*16 + seg*4, v);
      *(ull*)(enc_out + (size_t)(es*B_ + mt*16+row)*2048 + dir*H_ + jtb*16 + seg*4) = v;
    }
    gfull<64>(arrE, goE, (unsigned)(s+2), bid);
  }
}

// ---- decoder: 128 blocks, roles via g3=bid>>3, x=bid&7 ----
// S: g3 0..3  (b = 4x+g3)          -> scores (waits syncA)
// G: g3 4..9                        -> gh = h@Whh^T + bhh (MFMA, skips syncA)
// P: g3 12,13                       -> hW1 = h@W1h^T (MFMA, arrives syncA)
// D: all 128: db = 4x+(g3&3), jq = g3>>2
__global__ __launch_bounds__(256) void dec_loop_k(
  const float* __restrict__ gi_base,
  const bf16* __restrict__ encW1b,     // [2048][1024]
  const bf16* __restrict__ encWgb,     // [2048][3072]
  const bf16* __restrict__ whhd,       // [3072][1024]
  const float* __restrict__ bhhd,
  const bf16* __restrict__ w1b,        // [1024][3072]
  const float* __restrict__ attnW2,    // [1024]
  const float* __restrict__ dinh,      // [1024]
  bf16* __restrict__ hdb,              // [32][1024] device
  bf16* __restrict__ hW1b,             // [32][1024] device
  float* __restrict__ gh,              // [32][3072] device
  float* __restrict__ sc_t,            // [32][64]   device
  bf16* __restrict__ h_all,            // [2048][1024] normal
  unsigned* __restrict__ bar)
{
  __shared__ bf16 hst[16][1032];       // h staging (P/G)
  __shared__ float ghT[16][128];       // G transpose buffer / P reuses low part
  __shared__ bf16 hwT[16][128];        // P transpose buffer
  __shared__ float sW1[1024];          // S: hW1[b] as f32
  __shared__ float w2st[1024];
  __shared__ float scst[64];
  __shared__ float scall[2048];        // D: all scores
  __shared__ float watst[64];
  __shared__ float part[4][3][256];    // D partials
  __shared__ bf16 hnewst[256];
  unsigned* arrA = bar + 96;  unsigned* goA = bar + 120;
  unsigned* arrB = bar + 128; unsigned* goB = bar + 260;
  unsigned* arrC = bar + 288; unsigned* goC = bar + 420;
  const int tid = threadIdx.x, bid = blockIdx.x;
  const int w = tid>>6, l = tid&63;
  const int lr = l&15, koff = (l>>4)*8;
  const int x = bid&7, g3 = bid>>3;
  const bool isS = (g3 < 4), isG = (g3 >= 4 && g3 < 10), isP = (g3 == 12 || g3 == 13);
  const int b_s = 4*x + g3;            // S batch row
  const int db = 4*x + (g3&3), jq = g3>>2;
  const int jD = jq*256 + tid;         // this thread's GRU element

  w2st[tid] = attnW2[tid];
  w2st[tid+256] = attnW2[tid+256];
  w2st[tid+512] = attnW2[tid+512];
  w2st[tid+768] = attnW2[tid+768];

  float hreg = dinh[jD];
  hnewst[tid] = f2b(hreg);
  __syncthreads();
  if (tid < 64) dst64(hdb + db*H_ + jq*256 + tid*4, *(ull*)&hnewst[tid*4]);
  gfull<128>(arrC, goC, 1u, bid);

  for (int t = 0; t < 64; ++t){
    const unsigned epS = (unsigned)(t+1);
    // ================= phase 1: P & G (MFMA producers) =================
    if (isP){
      const int pmt = g3 - 12;
      const int pidx = x*2 + pmt;
      {
        const bf16* src = hdb + (size_t)pmt*16*H_;
        #pragma unroll
        for (int c = 0; c < 16; ++c){
          int g = c*256 + tid;
          *(ull*)&hst[g>>8][(g&255)*4] = dld64(src + g*4);
        }
      }
      __syncthreads();
      const int pjt0 = x*8 + w*2;
      #pragma unroll
      for (int q = 0; q < 2; ++q){
        const bf16* pb = w1b + (size_t)((pjt0+q)*16 + lr)*H3_ + 2048 + koff;
        f4 acc = (f4){0,0,0,0};
        #pragma unroll 4
        for (int k0 = 0; k0 < H_; k0 += 32)
          acc = MFMA16(*(const s8v*)&hst[lr][koff+k0], *(const s8v*)(pb+k0), acc);
        #pragma unroll
        for (int r = 0; r < 4; ++r)
          hwT[(l>>4)*4+r][(w*2+q)*16 + lr] = f2b(acc[r]);
      }
      __syncthreads();
      #pragma unroll
      for (int i = 0; i < 2; ++i){
        int idx = tid + i*256;
        int row = idx>>5, seg = idx&31;
        dst64(hW1b + (size_t)(pmt*16+row)*H_ + x*128 + seg*4, *(ull*)&hwT[row][seg*4]);
      }
      __syncthreads();                  // drain stores before arrival
      if (tid == 0) dstu(arrA + pidx, epS);
    }
    if (isG){
      const int gk = g3 - 4;
      const int gmt = gk/3, gkk = gk%3;
      {
        const bf16* src = hdb + (size_t)gmt*16*H_;
        #pragma unroll
        for (int c = 0; c < 16; ++c){
          int g = c*256 + tid;
          *(ull*)&hst[g>>8][(g&255)*4] = dld64(src + g*4);
        }
      }
      __syncthreads();
      const int ntb = x*24 + gkk*8;
      #pragma unroll
      for (int q = 0; q < 2; ++q){
        const int nt = ntb + w*2 + q;
        const bf16* pb = whhd + (size_t)(nt*16 + lr)*H_ + koff;
        const float bv = bhhd[nt*16 + lr];
        f4 acc = (f4){0,0,0,0};
        #pragma unroll 4
        for (int k0 = 0; k0 < H_; k0 += 32)
          acc = MFMA16(*(const s8v*)&hst[lr][koff+k0], *(const s8v*)(pb+k0), acc);
        #pragma unroll
        for (int r = 0; r < 4; ++r)
          ghT[(l>>4)*4+r][(w*2+q)*16 + lr] = acc[r] + bv;
      }
      __syncthreads();
      #pragma unroll
      for (int i = 0; i < 4; ++i){
        int idx = tid + i*256;              // 1024 tasks: 16 rows x 64 segs(8B)
        int row = idx>>6, seg = idx&63;
        union{ float f[2]; ull u; } pk;
        pk.f[0] = ghT[row][seg*2]; pk.f[1] = ghT[row][seg*2+1];
        dst64(gh + (size_t)(gmt*16+row)*H3_ + ntb*16 + seg*2, pk.u);
      }
    }
    // ================= syncA: P -> S =================
    if (isS){
      __syncthreads();
      if (bid == 0){
        if (tid < 64){
          for(;;){
            bool ok = (tid >= 16) || (dldu(arrA + tid) >= epS);
            if (__all(ok)) break;
            __builtin_amdgcn_s_sleep(1);
          }
          if (tid == 0) dstu(goA, epS);
        }
      } else if (tid == 0){
        while (dldu(goA) < epS) __builtin_amdgcn_s_sleep(1);
      }
      __syncthreads();
      asm volatile("" ::: "memory");
      // stage hW1[b_s] -> f32 LDS
      {
        union{ ull u; unsigned short us[4]; } v;
        v.u = dld64(hW1b + (size_t)b_s*H_ + tid*4);
        #pragma unroll
        for (int k=0;k<4;k++) sW1[tid*4+k] = bfu2f(v.us[k]);
      }
      __syncthreads();
      // scores: thread (s=tid>>2, jp=tid&3), 256 j each
      const int s = tid>>2, jp = tid&3;
      const bf16* e = encW1b + ((size_t)s*B_ + b_s)*H_ + jp*256;
      float p = 0.f;
      #pragma unroll 4
      for (int i = 0; i < 64; ++i){
        union{ ull u; unsigned short us[4]; } ev;
        ev.u = *(const ull*)(e + i*4);
        #pragma unroll
        for (int k = 0; k < 4; ++k){
          int j = jp*256 + i*4 + k;
          float xx = bfu2f(ev.us[k]) + sW1[j];
          p += w2st[j]*ftanh(xx);
        }
      }
      p += __shfl_xor(p,1); p += __shfl_xor(p,2);
      if ((tid&3)==0) scst[s] = p;
      __syncthreads();
      if (tid < 32) dst64(sc_t + b_s*64 + tid*2, *(ull*)&scst[tid*2]);
    }
    // ================= syncB: everyone =================
    gfull<128>(arrB, goB, epS, bid);
    // ================= phase D =================
    {
      #pragma unroll
      for (int q = 0; q < 4; ++q)
        *(ull*)&scall[tid*8 + q*2] = dld64(sc_t + tid*8 + q*2);
      __syncthreads();
      if (tid < 64){
        float m = -1e30f;
        #pragma unroll 8
        for (int b = 0; b < 32; ++b) m = fmaxf(m, scall[b*64 + tid]);
        float sum = 0.f;
        #pragma unroll 8
        for (int b = 0; b < 32; ++b) sum += __expf(scall[b*64 + tid] - m);
        watst[tid] = __expf(scall[db*64 + tid] - m)/sum;
      }
      __syncthreads();
      // weighted sum: wave wv handles 16 s2, lane covers 4 j
      const int lane = tid&63, wv = tid>>6;
      const int j0 = jq*256 + lane*4;
      f4 g0 = (f4){0,0,0,0}, g1 = (f4){0,0,0,0}, g2 = (f4){0,0,0,0};
      #pragma unroll 4
      for (int i = 0; i < 16; ++i){
        const int s2 = wv*16 + i;
        const float wt = watst[s2];
        const bf16* ro = encWgb + ((size_t)s2*B_ + db)*H3_;
        union{ ull u; unsigned short us[4]; } v0, v1, v2;
        v0.u = *(const ull*)(ro + j0);
        v1.u = *(const ull*)(ro + H_ + j0);
        v2.u = *(const ull*)(ro + 2*H_ + j0);
        #pragma unroll
        for (int k = 0; k < 4; ++k){
          g0[k] += wt*bfu2f(v0.us[k]);
          g1[k] += wt*bfu2f(v1.us[k]);
          g2[k] += wt*bfu2f(v2.us[k]);
        }
      }
      *(f4*)&part[wv][0][lane*4] = g0;
      *(f4*)&part[wv][1][lane*4] = g1;
      *(f4*)&part[wv][2][lane*4] = g2;
      __syncthreads();
      float G0 = part[0][0][tid]+part[1][0][tid]+part[2][0][tid]+part[3][0][tid];
      float G1 = part[0][1][tid]+part[1][1][tid]+part[2][1][tid]+part[3][1][tid];
      float G2 = part[0][2][tid]+part[1][2][tid]+part[2][2][tid]+part[3][2][tid];
      const float* gp = gi_base + ((size_t)t*B_ + db)*H3_ + jD;
      float ir  = gp[0]    + G0;
      float iz  = gp[H_]   + G1;
      float inn = gp[2*H_] + G2;
      float hr_ = dldf(gh + (size_t)db*H3_ + jD);
      float hz_ = dldf(gh + (size_t)db*H3_ + H_ + jD);
      float hn_ = dldf(gh + (size_t)db*H3_ + 2*H_ + jD);
      float rg = fsigmoid(ir + hr_);
      float zg = fsigmoid(iz + hz_);
      float ng = ftanh(inn + rg*hn_);
      float hnew = (1.f - zg)*ng + zg*hreg;
      hreg = hnew;
      hnewst[tid] = f2b(hnew);
      __syncthreads();
      if (tid < 64){
        ull v = *(ull*)&hnewst[tid*4];
        dst64(hdb + (size_t)db*H_ + jq*256 + tid*4, v);
        *(ull*)(h_all + ((size_t)t*B_ + db)*H_ + jq*256 + tid*4) = v;
      }
    }
    // ================= syncC =================
    gfull<128>(arrC, goC, (unsigned)(t+2), bid);
  }
}

// ---- 2-pass online row softmax over V ----
__global__ __launch_bounds__(256) void softmax_rows_k(float* __restrict__ out){
  __shared__ float wm[4], wl[4];
  const int tid = threadIdx.x;
  float* p = out + (size_t)blockIdx.x*V_;
  float m = -1e30f, lsum = 0.f;
  for (int j = tid; j < V_; j += 256){
    float v = p[j];
    float mn = fmaxf(m, v);
    lsum = lsum*__expf(m - mn) + __expf(v - mn);
    m = mn;
  }
  #pragma unroll
  for (int o = 32; o; o >>= 1){
    float mo = __shfl_xor(m, o), lo_ = __shfl_xor(lsum, o);
    float mn = fmaxf(m, mo);
    lsum = lsum*__expf(m - mn) + lo_*__expf(mo - mn);
    m = mn;
  }
  if ((tid&63)==0){ wm[tid>>6] = m; wl[tid>>6] = lsum; }
  __syncthreads();
  float M = fmaxf(fmaxf(wm[0],wm[1]), fmaxf(wm[2],wm[3]));
  float L = wl[0]*__expf(wm[0]-M) + wl[1]*__expf(wm[1]-M)
          + wl[2]*__expf(wm[2]-M) + wl[3]*__expf(wm[3]-M);
  float inv = 1.f/L;
  for (int j = tid; j < V_; j += 256) p[j] = __expf(p[j]-M)*inv;
}

extern "C" void kernel_launch(void* const* d_in, const int* in_sizes, int n_in,
                              void* d_out, int out_size, void* d_ws, size_t ws_size,
                              hipStream_t stream)
{
  (void)in_sizes; (void)n_in; (void)out_size; (void)ws_size;
  const int*   iseq  = (const int*)d_in[0];
  const int*   tseq  = (const int*)d_in[1];
  const float* emb   = (const float*)d_in[2];
  const float* wihf  = (const float*)d_in[3];
  const float* whhf_f= (const float*)d_in[4];
  const float* bihf  = (const float*)d_in[5];
  const float* bhhf  = (const float*)d_in[6];
  const float* wihb  = (const float*)d_in[7];
  const float* whhb_f= (const float*)d_in[8];
  const float* bihb  = (const float*)d_in[9];
  const float* bhhb  = (const float*)d_in[10];
  const float* einit = (const float*)d_in[11];
  const float* wihd  = (const float*)d_in[12];
  const float* whhd_f= (const float*)d_in[13];
  const float* bihd  = (const float*)d_in[14];
  const float* bhhd  = (const float*)d_in[15];
  const float* dinh  = (const float*)d_in[16];
  const float* dino  = (const float*)d_in[17];
  const float* w1    = (const float*)d_in[18];
  const float* w2    = (const float*)d_in[19];
  const float* outw  = (const float*)d_in[20];
  const float* outb  = (const float*)d_in[21];
  float* out = (float*)d_out;

  char* ws = (char*)d_ws;
  size_t off = 0;
  auto alloc = [&](size_t bytes)->char*{ char* p = ws + off; off += (bytes + 255) & ~(size_t)255; return p; };
  unsigned* bar  = (unsigned*)alloc(2048);
  bf16* x_b      = (bf16*)alloc((size_t)2048*512*2);
  bf16* lo_b     = (bf16*)alloc((size_t)2048*512*2);
  bf16* wihf_b   = (bf16*)alloc((size_t)3072*512*2);
  bf16* wihb_b   = (bf16*)alloc((size_t)3072*512*2);
  bf16* whhf_b   = (bf16*)alloc((size_t)3072*1024*2);
  bf16* whhb_b   = (bf16*)alloc((size_t)3072*1024*2);
  bf16* wihd_b   = (bf16*)alloc((size_t)3072*3072*2);
  bf16* whhd_b   = (bf16*)alloc((size_t)3072*1024*2);
  bf16* w1_b     = (bf16*)alloc((size_t)1024*3072*2);
  bf16* outw_b   = (bf16*)alloc((size_t)32000*1024*2);
  float* gi_f    = (float*)alloc((size_t)2048*3072*4);
  float* gi_b    = (float*)alloc((size_t)2048*3072*4);
  float* gi_d    = (float*)alloc((size_t)2048*3072*4);
  bf16* enc_b    = (bf16*)alloc((size_t)2048*2048*2);
  bf16* encW1_b  = (bf16*)alloc((size_t)2048*1024*2);
  bf16* encWg_b  = (bf16*)alloc((size_t)2048*3072*2);
  bf16*  henc_b  = (bf16*)alloc((size_t)2*65536*2);
  bf16*  hdb     = (bf16*)alloc((size_t)32768*2);
  bf16*  hW1b    = (bf16*)alloc((size_t)32768*2);
  float* ghb     = (float*)alloc((size_t)32*3072*4);
  float* sc_t    = (float*)alloc((size_t)32*64*4);
  bf16*  hall_b  = (bf16*)alloc((size_t)2048*1024*2);

  hipMemsetAsync(bar, 0, 2048, stream);

  auto cgrid = [](int n8){ int g = (n8 + 255)/256; return g > 2048 ? 2048 : g; };
  gather_x_k <<<512, 256, 0, stream>>>(emb, iseq, x_b);
  gather_lo_k<<<512, 256, 0, stream>>>(emb, tseq, dino, lo_b);
  cast_bf16_k<<<cgrid(196608),  256, 0, stream>>>(wihf,   wihf_b, 196608);
  cast_bf16_k<<<cgrid(196608),  256, 0, stream>>>(wihb,   wihb_b, 196608);
  cast_bf16_k<<<cgrid(393216),  256, 0, stream>>>(whhf_f, whhf_b, 393216);
  cast_bf16_k<<<cgrid(393216),  256, 0, stream>>>(whhb_f, whhb_b, 393216);
  cast_bf16_k<<<cgrid(1179648), 256, 0, stream>>>(wihd,   wihd_b, 1179648);
  cast_bf16_k<<<cgrid(393216),  256, 0, stream>>>(whhd_f, whhd_b, 393216);
  cast_bf16_k<<<cgrid(393216),  256, 0, stream>>>(w1,     w1_b,   393216);
  cast_bf16_k<<<cgrid(4096000), 256, 0, stream>>>(outw,   outw_b, 4096000);

  gemm_bt<0,0><<<dim3(24,16), 256, 0, stream>>>(x_b, 512, wihf_b,      512,  bihf,    gi_f, 3072, 512);
  gemm_bt<0,0><<<dim3(24,16), 256, 0, stream>>>(x_b, 512, wihb_b,      512,  bihb,    gi_b, 3072, 512);
  gemm_bt<0,0><<<dim3(24,16), 256, 0, stream>>>(x_b, 512, wihd_b,      3072, bihd,    gi_d, 3072, 512);
  gemm_bt<0,1><<<dim3(24,16), 256, 0, stream>>>(lo_b,512, wihd_b+2560, 3072, nullptr, gi_d, 3072, 512);

  enc_loop_k<<<64, 256, 0, stream>>>(gi_f, gi_b, whhf_b, whhb_b, bhhf, bhhb, einit,
                                     henc_b, enc_b, bar);

  gemm_bt<1,0><<<dim3(8,16),  256, 0, stream>>>(enc_b, 2048, w1_b,       3072, nullptr, encW1_b, 1024, 2048);
  gemm_bt<1,0><<<dim3(24,16), 256, 0, stream>>>(enc_b, 2048, wihd_b+512, 3072, nullptr, encWg_b, 3072, 2048);

  dec_loop_k<<<128, 256, 0, stream>>>(gi_d, encW1_b, encWg_b, whhd_b, bhhd, w1_b, w2, dinh,
                                      hdb, hW1b, ghb, sc_t, hall_b, bar);

  gemm_bt<0,0><<<dim3(250,16), 256, 0, stream>>>(hall_b, 1024, outw_b, 1024, outb, out, 32000, 1024);
  softmax_rows_k<<<2048, 256, 0, stream>>>(out);
}

// Round 6
// 3279.219 us; speedup vs baseline: 1.4535x; 1.3385x over previous
//
#include <hip/hip_runtime.h>
#include <hip/hip_bf16.h>

#define S_ 64
#define B_ 32
#define V_ 32000
#define E_ 512
#define H_ 1024
#define H3_ 3072

typedef __hip_bfloat16 bf16;
typedef __attribute__((ext_vector_type(8))) short s8v;
typedef __attribute__((ext_vector_type(4))) float f4;
typedef unsigned long long ull;

__device__ __forceinline__ float b2f(bf16 x){ return __bfloat162float(x); }
__device__ __forceinline__ bf16  f2b(float x){ return __float2bfloat16(x); }
__device__ __forceinline__ float bfu2f(unsigned short u){
  union { unsigned u; float f; } c; c.u = ((unsigned)u) << 16; return c.f;
}
#define MFMA16(a,b,c) __builtin_amdgcn_mfma_f32_16x16x32_bf16((a),(b),(c),0,0,0)

__device__ __forceinline__ float fsigmoid(float x){ return 1.f/(1.f + __expf(-x)); }
__device__ __forceinline__ float ftanh(float x){ float e2 = __expf(2.f*x); return 1.f - 2.f/(e2 + 1.f); }

// ---- prep kernels ----
__global__ __launch_bounds__(256) void cast_bf16_k(const float* __restrict__ s, bf16* __restrict__ d, int n8){
  int stride = gridDim.x*256;
  for (int i = blockIdx.x*256 + threadIdx.x; i < n8; i += stride){
    f4 a = *((const f4*)s + (size_t)i*2);
    f4 b = *((const f4*)s + (size_t)i*2 + 1);
    union { s8v v; bf16 h[8]; } o;
    #pragma unroll
    for (int k=0;k<4;k++){ o.h[k]=f2b(a[k]); o.h[4+k]=f2b(b[k]); }
    *((s8v*)d + i) = o.v;
  }
}
__global__ __launch_bounds__(256) void gather_x_k(const float* __restrict__ emb, const int* __restrict__ seq, bf16* __restrict__ d){
  int i = blockIdx.x*256 + threadIdx.x;
  int row = i >> 6, e8 = i & 63;
  const float* src = emb + (size_t)seq[row]*E_;
  f4 a = *((const f4*)src + e8*2);
  f4 b = *((const f4*)src + e8*2 + 1);
  union { s8v v; bf16 h[8]; } o;
  #pragma unroll
  for (int k=0;k<4;k++){ o.h[k]=f2b(a[k]); o.h[4+k]=f2b(b[k]); }
  *((s8v*)d + i) = o.v;
}
__global__ __launch_bounds__(256) void gather_lo_k(const float* __restrict__ emb, const int* __restrict__ tseq, const float* __restrict__ o0, bf16* __restrict__ d){
  int i = blockIdx.x*256 + threadIdx.x;
  int row = i >> 6, e8 = i & 63;
  int t = row >> 5, b = row & 31;
  const float* src = (t == 0) ? o0 : (emb + (size_t)tseq[(t-1)*B_ + b]*E_);
  f4 a = *((const f4*)src + e8*2);
  f4 c = *((const f4*)src + e8*2 + 1);
  union { s8v v; bf16 h[8]; } o;
  #pragma unroll
  for (int k=0;k<4;k++){ o.h[k]=f2b(a[k]); o.h[4+k]=f2b(c[k]); }
  *((s8v*)d + i) = o.v;
}

// ---- generic bf16 MFMA GEMM ----
template<int WB16, int ACC>
__global__ __launch_bounds__(256) void gemm_bt(const bf16* __restrict__ A, int lda,
                                               const bf16* __restrict__ B, int ldb,
                                               const float* __restrict__ bias,
                                               void* __restrict__ Cp, int ldc, int K)
{
  __shared__ bf16 a_sm[128][40];
  __shared__ bf16 b_sm[128][40];
  const int tid = threadIdx.x;
  const int m0 = blockIdx.y*128, n0 = blockIdx.x*128;
  const int w = tid>>6, l = tid&63;
  const int wm = w>>1, wn = w&1;
  f4 acc[4][4];
  #pragma unroll
  for (int i=0;i<4;i++)
    #pragma unroll
    for (int j=0;j<4;j++) acc[i][j] = (f4){0.f,0.f,0.f,0.f};
  const int srow = tid>>1, skc = (tid&1)*16;
  const int ar = l&15, koff = (l>>4)*8;
  for (int k0 = 0; k0 < K; k0 += 32){
    __syncthreads();
    const s8v* pa = (const s8v*)(A + (size_t)(m0+srow)*lda + k0 + skc);
    const s8v* pb = (const s8v*)(B + (size_t)(n0+srow)*ldb + k0 + skc);
    *(s8v*)&a_sm[srow][skc]   = pa[0];
    *(s8v*)&a_sm[srow][skc+8] = pa[1];
    *(s8v*)&b_sm[srow][skc]   = pb[0];
    *(s8v*)&b_sm[srow][skc+8] = pb[1];
    __syncthreads();
    s8v av[4], bv[4];
    #pragma unroll
    for (int i=0;i<4;i++) av[i] = *(const s8v*)&a_sm[wm*64 + i*16 + ar][koff];
    #pragma unroll
    for (int j=0;j<4;j++) bv[j] = *(const s8v*)&b_sm[wn*64 + j*16 + ar][koff];
    #pragma unroll
    for (int i=0;i<4;i++)
      #pragma unroll
      for (int j=0;j<4;j++)
        acc[i][j] = MFMA16(av[i], bv[j], acc[i][j]);
  }
  const int rb = (l>>4)*4;
  #pragma unroll
  for (int i=0;i<4;i++){
    #pragma unroll
    for (int j=0;j<4;j++){
      int col = n0 + wn*64 + j*16 + ar;
      float badd = bias ? bias[col] : 0.f;
      #pragma unroll
      for (int r=0;r<4;r++){
        int row = m0 + wm*64 + i*16 + rb + r;
        size_t idx = (size_t)row*ldc + col;
        float v = acc[i][j][r] + badd;
        if (ACC) v += ((const float*)Cp)[idx];
        if (WB16) ((bf16*)Cp)[idx] = f2b(v);
        else      ((float*)Cp)[idx] = v;
      }
    }
  }
}

// ---- init kernels ----
__global__ __launch_bounds__(256) void enc_init_k(const float* __restrict__ enc_init,
                                                  bf16* __restrict__ hb0, float* __restrict__ hfE){
  int i = blockIdx.x*256 + threadIdx.x;       // 0..8191 (x8 elems)
  int base = i*8;
  int dir = base>>15, rem = base&32767, col = rem&1023;
  const float* sp = enc_init + dir*H_ + col;
  f4 a = *(const f4*)sp, b = *(const f4*)(sp+4);
  union { s8v v; bf16 h[8]; } o;
  #pragma unroll
  for (int k=0;k<4;k++){ o.h[k]=f2b(a[k]); o.h[4+k]=f2b(b[k]); }
  *(s8v*)(hb0 + dir*32768 + rem) = o.v;
  *(f4*)(hfE + dir*32768 + rem) = a;
  *(f4*)(hfE + dir*32768 + rem + 4) = b;
}
__global__ __launch_bounds__(256) void dec_init_k(const float* __restrict__ dinh,
                                                  bf16* __restrict__ hd0, float* __restrict__ hfD){
  int i = blockIdx.x*256 + threadIdx.x;       // 0..4095 (x8)
  int base = i*8;
  int col = base&1023;
  const float* sp = dinh + col;
  f4 a = *(const f4*)sp, b = *(const f4*)(sp+4);
  union { s8v v; bf16 h[8]; } o;
  #pragma unroll
  for (int k=0;k<4;k++){ o.h[k]=f2b(a[k]); o.h[4+k]=f2b(b[k]); }
  *(s8v*)(hd0 + base) = o.v;
  *(f4*)(hfD + base) = a;
  *(f4*)(hfD + base + 4) = b;
}

// ---- encoder: ONE STEP per launch, 64 blocks ----
// map: x=bid&7, g3=bid>>3: dir=x>>2, mt=g3>>2, jtb=(x&3)*16+(g3&3)*4, jt=jtb+w
__global__ __launch_bounds__(256) void enc_step_k(
  const float* __restrict__ gi_f, const float* __restrict__ gi_b,
  const bf16* __restrict__ whhf, const bf16* __restrict__ whhb,
  const float* __restrict__ bhhf, const float* __restrict__ bhhb,
  const bf16* __restrict__ hrd_base,   // hb + (s&1)*65536
  bf16* __restrict__ hwr_base,         // hb + ((s+1)&1)*65536
  float* __restrict__ hfE,             // [2][32][1024] fp32 master
  bf16* __restrict__ enc_out, int s)
{
  __shared__ bf16 hst[16][1032];
  __shared__ bf16 hsT[16][64];
  const int tid = threadIdx.x, bid = blockIdx.x;
  const int w = tid>>6, l = tid&63;
  const int lr = l&15, koff = (l>>4)*8, rb = (l>>4)*4;
  const int x = bid&7, g3 = bid>>3;
  const int dir = x>>2;
  const int mt = g3>>2;
  const int jtb = (x&3)*16 + (g3&3)*4;
  const int jt = jtb + w;
  const int col = jt*16 + lr;
  const bf16* W    = dir ? whhb : whhf;
  const float* gi  = dir ? gi_b : gi_f;
  const float* bhh = dir ? bhhb : bhhf;
  const float br_ = bhh[col], bz_ = bhh[H_+col], bn_ = bhh[2*H_+col];
  const bf16* pr = W + (size_t)(jt*16 + lr)*H_ + koff;
  const bf16* pz = pr + (size_t)H_*H_;
  const bf16* pn = pz + (size_t)H_*H_;
  // stage my 16 h rows -> LDS (plain cached loads)
  {
    const bf16* src = hrd_base + dir*32768 + (size_t)mt*16*H_;
    #pragma unroll
    for (int c = 0; c < 8; ++c){
      int g = c*256 + tid;               // 2048 chunks of 16B
      int row = g>>7, off = g&127;
      *(s8v*)&hst[row][off*8] = *(const s8v*)(src + (size_t)row*H_ + off*8);
    }
  }
  __syncthreads();
  f4 accr = (f4){0,0,0,0}, accz = (f4){0,0,0,0}, accn = (f4){0,0,0,0};
  #pragma unroll 4
  for (int k0 = 0; k0 < H_; k0 += 32){
    s8v a = *(const s8v*)&hst[lr][koff + k0];
    accr = MFMA16(a, *(const s8v*)(pr + k0), accr);
    accz = MFMA16(a, *(const s8v*)(pz + k0), accz);
    accn = MFMA16(a, *(const s8v*)(pn + k0), accn);
  }
  const int es = dir ? (63 - s) : s;
  #pragma unroll
  for (int ri = 0; ri < 4; ++ri){
    const int b_ = mt*16 + rb + ri;
    const size_t gr = (size_t)(es*B_ + b_)*H3_;
    float ir = gi[gr + col], iz = gi[gr + H_ + col], inn = gi[gr + 2*H_ + col];
    float rg = fsigmoid(ir + accr[ri] + br_);
    float zg = fsigmoid(iz + accz[ri] + bz_);
    float ng = ftanh(inn + rg*(accn[ri] + bn_));
    float hold = hfE[dir*32768 + b_*H_ + col];
    float hnew = (1.f - zg)*ng + zg*hold;
    hfE[dir*32768 + b_*H_ + col] = hnew;
    hsT[rb+ri][w*16+lr] = f2b(hnew);
  }
  __syncthreads();
  {
    const int row = tid>>4, seg = tid&15;
    ull v = *(ull*)&hsT[row][seg*4];
    *(ull*)(hwr_base + dir*32768 + (size_t)(mt*16+row)*H_ + jtb*16 + seg*4) = v;
    *(ull*)(enc_out + (size_t)(es*B_ + mt*16+row)*2048 + dir*H_ + jtb*16 + seg*4) = v;
  }
}

// ---- decoder k1: gh = h@Whh^T + bhh  AND  hW1 = h@W1h^T.  64 blocks ----
// bid<16: P (pmt=bid&1, x=bid>>1).  bid>=16: G (gb=bid-16: gmt=gb&1, rest=gb>>1: x=rest/3, gkk=rest%3)
__global__ __launch_bounds__(256) void dec_k1(
  const bf16* __restrict__ hd,         // [32][1024] read buffer
  const bf16* __restrict__ whhd, const float* __restrict__ bhhd,
  const bf16* __restrict__ w1b,
  float* __restrict__ gh, bf16* __restrict__ hW1b)
{
  __shared__ bf16 hst[16][1032];
  __shared__ float ghT[16][128];
  __shared__ bf16 hwT[16][128];
  const int tid = threadIdx.x, bid = blockIdx.x;
  const int w = tid>>6, l = tid&63;
  const int lr = l&15, koff = (l>>4)*8;
  const bool isP = bid < 16;
  const int hmt = isP ? (bid&1) : ((bid-16)&1);
  {
    const bf16* src = hd + (size_t)hmt*16*H_;
    #pragma unroll
    for (int c = 0; c < 8; ++c){
      int g = c*256 + tid;
      int row = g>>7, off = g&127;
      *(s8v*)&hst[row][off*8] = *(const s8v*)(src + (size_t)row*H_ + off*8);
    }
  }
  __syncthreads();
  if (isP){
    const int x2 = bid>>1;
    const int pjt0 = x2*8 + w*2;
    #pragma unroll
    for (int q = 0; q < 2; ++q){
      const bf16* pb = w1b + (size_t)((pjt0+q)*16 + lr)*H3_ + 2048 + koff;
      f4 acc = (f4){0,0,0,0};
      #pragma unroll 4
      for (int k0 = 0; k0 < H_; k0 += 32)
        acc = MFMA16(*(const s8v*)&hst[lr][koff+k0], *(const s8v*)(pb+k0), acc);
      #pragma unroll
      for (int r = 0; r < 4; ++r)
        hwT[(l>>4)*4+r][(w*2+q)*16 + lr] = f2b(acc[r]);
    }
    __syncthreads();
    #pragma unroll
    for (int i = 0; i < 2; ++i){
      int idx = tid + i*256;
      int row = idx>>5, seg = idx&31;
      *(ull*)(hW1b + (size_t)(hmt*16+row)*H_ + x2*128 + seg*4) = *(ull*)&hwT[row][seg*4];
    }
  } else {
    const int gb = bid - 16;
    const int rest = gb>>1;
    const int x3 = rest/3, gkk = rest%3;
    const int ntb = x3*24 + gkk*8;
    #pragma unroll
    for (int q = 0; q < 2; ++q){
      const int nt = ntb + w*2 + q;
      const bf16* pb = whhd + (size_t)(nt*16 + lr)*H_ + koff;
      const float bv = bhhd[nt*16 + lr];
      f4 acc = (f4){0,0,0,0};
      #pragma unroll 4
      for (int k0 = 0; k0 < H_; k0 += 32)
        acc = MFMA16(*(const s8v*)&hst[lr][koff+k0], *(const s8v*)(pb+k0), acc);
      #pragma unroll
      for (int r = 0; r < 4; ++r)
        ghT[(l>>4)*4+r][(w*2+q)*16 + lr] = acc[r] + bv;
    }
    __syncthreads();
    #pragma unroll
    for (int i = 0; i < 4; ++i){
      int idx = tid + i*256;
      int row = idx>>6, seg = idx&63;
      union{ float f[2]; ull u; } pk;
      pk.f[0] = ghT[row][seg*2]; pk.f[1] = ghT[row][seg*2+1];
      *(ull*)(gh + (size_t)(hmt*16+row)*H3_ + ntb*16 + seg*2) = pk.u;
    }
  }
}

// ---- decoder k2: scores + softmax over batch. 64 blocks (one per s) ----
__global__ __launch_bounds__(256) void dec_k2(
  const bf16* __restrict__ encW1b, const bf16* __restrict__ hW1b,
  const float* __restrict__ attnW2, float* __restrict__ wat)
{
  __shared__ float w2st[1024];
  __shared__ float scl[32];
  const int tid = threadIdx.x, s = blockIdx.x;
  w2st[tid] = attnW2[tid];
  w2st[tid+256] = attnW2[tid+256];
  w2st[tid+512] = attnW2[tid+512];
  w2st[tid+768] = attnW2[tid+768];
  __syncthreads();
  const int b = tid>>3, part = tid&7;
  const bf16* hp = hW1b + (size_t)b*H_ + part*128;
  const bf16* ep = encW1b + ((size_t)s*B_ + b)*H_ + part*128;
  const float* wp = w2st + part*128;
  float p = 0.f;
  #pragma unroll 4
  for (int ii = 0; ii < 16; ++ii){
    union { s8v v; unsigned short uu[8]; } hv, ev;
    hv.v = *(const s8v*)(hp + ii*8);
    ev.v = *(const s8v*)(ep + ii*8);
    #pragma unroll
    for (int k = 0; k < 8; ++k){
      float xx = bfu2f(ev.uu[k]) + bfu2f(hv.uu[k]);
      p += wp[ii*8+k]*ftanh(xx);
    }
  }
  p += __shfl_xor(p,1); p += __shfl_xor(p,2); p += __shfl_xor(p,4);
  if (part == 0) scl[b] = p;
  __syncthreads();
  if (tid < 32){
    float v = scl[tid];
    float m = v;
    #pragma unroll
    for (int o = 1; o <= 16; o <<= 1) m = fmaxf(m, __shfl_xor(m, o));
    float e = __expf(v - m);
    float Z = e;
    #pragma unroll
    for (int o = 1; o <= 16; o <<= 1) Z += __shfl_xor(Z, o);
    wat[s*B_ + tid] = e/Z;
  }
}

// ---- decoder k3: glimpse weighted sum + GRU pointwise. 128 blocks ----
__global__ __launch_bounds__(256) void dec_k3(
  const float* __restrict__ gi_t,      // gi_d + t*B*H3
  const bf16* __restrict__ encWgb, const float* __restrict__ gh,
  const float* __restrict__ wat,
  float* __restrict__ hfD, bf16* __restrict__ hd_w, bf16* __restrict__ hall_t)
{
  __shared__ float watst[64];
  __shared__ float part_[4][3][256];
  __shared__ bf16 hnewst[256];
  const int tid = threadIdx.x, bid = blockIdx.x;
  const int x = bid&7, g3 = bid>>3;
  const int db = 4*x + (g3&3), jq = g3>>2;
  const int jD = jq*256 + tid;
  if (tid < 64) watst[tid] = wat[tid*B_ + db];
  __syncthreads();
  const int lane = tid&63, wv = tid>>6;
  const int j0 = jq*256 + lane*4;
  f4 g0 = (f4){0,0,0,0}, g1 = (f4){0,0,0,0}, g2 = (f4){0,0,0,0};
  #pragma unroll 4
  for (int i = 0; i < 16; ++i){
    const int s2 = wv*16 + i;
    const float wt = watst[s2];
    const bf16* ro = encWgb + ((size_t)s2*B_ + db)*H3_;
    union{ ull u; unsigned short us[4]; } v0, v1, v2;
    v0.u = *(const ull*)(ro + j0);
    v1.u = *(const ull*)(ro + H_ + j0);
    v2.u = *(const ull*)(ro + 2*H_ + j0);
    #pragma unroll
    for (int k = 0; k < 4; ++k){
      g0[k] += wt*bfu2f(v0.us[k]);
      g1[k] += wt*bfu2f(v1.us[k]);
      g2[k] += wt*bfu2f(v2.us[k]);
    }
  }
  *(f4*)&part_[wv][0][lane*4] = g0;
  *(f4*)&part_[wv][1][lane*4] = g1;
  *(f4*)&part_[wv][2][lane*4] = g2;
  __syncthreads();
  float G0 = part_[0][0][tid]+part_[1][0][tid]+part_[2][0][tid]+part_[3][0][tid];
  float G1 = part_[0][1][tid]+part_[1][1][tid]+part_[2][1][tid]+part_[3][1][tid];
  float G2 = part_[0][2][tid]+part_[1][2][tid]+part_[2][2][tid]+part_[3][2][tid];
  const float* gp = gi_t + (size_t)db*H3_ + jD;
  float ir  = gp[0]    + G0;
  float iz  = gp[H_]   + G1;
  float inn = gp[2*H_] + G2;
  float hr_ = gh[(size_t)db*H3_ + jD];
  float hz_ = gh[(size_t)db*H3_ + H_ + jD];
  float hn_ = gh[(size_t)db*H3_ + 2*H_ + jD];
  float rg = fsigmoid(ir + hr_);
  float zg = fsigmoid(iz + hz_);
  float ng = ftanh(inn + rg*hn_);
  float hold = hfD[(size_t)db*H_ + jD];
  float hnew = (1.f - zg)*ng + zg*hold;
  hfD[(size_t)db*H_ + jD] = hnew;
  hnewst[tid] = f2b(hnew);
  __syncthreads();
  if (tid < 64){
    ull v = *(ull*)&hnewst[tid*4];
    *(ull*)(hd_w + (size_t)db*H_ + jq*256 + tid*4) = v;
    *(ull*)(hall_t + (size_t)db*H_ + jq*256 + tid*4) = v;
  }
}

// ---- 2-pass online row softmax over V ----
__global__ __launch_bounds__(256) void softmax_rows_k(float* __restrict__ out){
  __shared__ float wm[4], wl[4];
  const int tid = threadIdx.x;
  float* p = out + (size_t)blockIdx.x*V_;
  float m = -1e30f, lsum = 0.f;
  for (int j = tid; j < V_; j += 256){
    float v = p[j];
    float mn = fmaxf(m, v);
    lsum = lsum*__expf(m - mn) + __expf(v - mn);
    m = mn;
  }
  #pragma unroll
  for (int o = 32; o; o >>= 1){
    float mo = __shfl_xor(m, o), lo_ = __shfl_xor(lsum, o);
    float mn = fmaxf(m, mo);
    lsum = lsum*__expf(m - mn) + lo_*__expf(mo - mn);
    m = mn;
  }
  if ((tid&63)==0){ wm[tid>>6] = m; wl[tid>>6] = lsum; }
  __syncthreads();
  float M = fmaxf(fmaxf(wm[0],wm[1]), fmaxf(wm[2],wm[3]));
  float L = wl[0]*__expf(wm[0]-M) + wl[1]*__expf(wm[1]-M)
          + wl[2]*__expf(wm[2]-M) + wl[3]*__expf(wm[3]-M);
  float inv = 1.f/L;
  for (int j = tid; j < V_; j += 256) p[j] = __expf(p[j]-M)*inv;
}

extern "C" void kernel_launch(void* const* d_in, const int* in_sizes, int n_in,
                              void* d_out, int out_size, void* d_ws, size_t ws_size,
                              hipStream_t stream)
{
  (void)in_sizes; (void)n_in; (void)out_size; (void)ws_size;
  const int*   iseq  = (const int*)d_in[0];
  const int*   tseq  = (const int*)d_in[1];
  const float* emb   = (const float*)d_in[2];
  const float* wihf  = (const float*)d_in[3];
  const float* whhf_f= (const float*)d_in[4];
  const float* bihf  = (const float*)d_in[5];
  const float* bhhf  = (const float*)d_in[6];
  const float* wihb  = (const float*)d_in[7];
  const float* whhb_f= (const float*)d_in[8];
  const float* bihb  = (const float*)d_in[9];
  const float* bhhb  = (const float*)d_in[10];
  const float* einit = (const float*)d_in[11];
  const float* wihd  = (const float*)d_in[12];
  const float* whhd_f= (const float*)d_in[13];
  const float* bihd  = (const float*)d_in[14];
  const float* bhhd  = (const float*)d_in[15];
  const float* dinh  = (const float*)d_in[16];
  const float* dino  = (const float*)d_in[17];
  const float* w1    = (const float*)d_in[18];
  const float* w2    = (const float*)d_in[19];
  const float* outw  = (const float*)d_in[20];
  const float* outb  = (const float*)d_in[21];
  float* out = (float*)d_out;

  char* ws = (char*)d_ws;
  size_t off = 0;
  auto alloc = [&](size_t bytes)->char*{ char* p = ws + off; off += (bytes + 255) & ~(size_t)255; return p; };
  bf16* x_b      = (bf16*)alloc((size_t)2048*512*2);
  bf16* lo_b     = (bf16*)alloc((size_t)2048*512*2);
  bf16* wihf_b   = (bf16*)alloc((size_t)3072*512*2);
  bf16* wihb_b   = (bf16*)alloc((size_t)3072*512*2);
  bf16* whhf_b   = (bf16*)alloc((size_t)3072*1024*2);
  bf16* whhb_b   = (bf16*)alloc((size_t)3072*1024*2);
  bf16* wihd_b   = (bf16*)alloc((size_t)3072*3072*2);
  bf16* whhd_b   = (bf16*)alloc((size_t)3072*1024*2);
  bf16* w1_b     = (bf16*)alloc((size_t)1024*3072*2);
  bf16* outw_b   = (bf16*)alloc((size_t)32000*1024*2);
  float* gi_f    = (float*)alloc((size_t)2048*3072*4);
  float* gi_b    = (float*)alloc((size_t)2048*3072*4);
  float* gi_d    = (float*)alloc((size_t)2048*3072*4);
  bf16* enc_b    = (bf16*)alloc((size_t)2048*2048*2);
  bf16* encW1_b  = (bf16*)alloc((size_t)2048*1024*2);
  bf16* encWg_b  = (bf16*)alloc((size_t)2048*3072*2);
  bf16*  henc_b  = (bf16*)alloc((size_t)2*65536*2);   // ping-pong [2][2][32][1024]
  float* hfE     = (float*)alloc((size_t)2*32768*4);  // fp32 master [2][32][1024]
  bf16*  hdb     = (bf16*)alloc((size_t)2*32768*2);   // ping-pong [2][32][1024]
  float* hfD     = (float*)alloc((size_t)32768*4);
  bf16*  hW1b    = (bf16*)alloc((size_t)32768*2);
  float* ghb     = (float*)alloc((size_t)32*3072*4);
  float* wat     = (float*)alloc((size_t)64*32*4);
  bf16*  hall_b  = (bf16*)alloc((size_t)2048*1024*2);

  auto cgrid = [](int n8){ int g = (n8 + 255)/256; return g > 2048 ? 2048 : g; };
  gather_x_k <<<512, 256, 0, stream>>>(emb, iseq, x_b);
  gather_lo_k<<<512, 256, 0, stream>>>(emb, tseq, dino, lo_b);
  cast_bf16_k<<<cgrid(196608),  256, 0, stream>>>(wihf,   wihf_b, 196608);
  cast_bf16_k<<<cgrid(196608),  256, 0, stream>>>(wihb,   wihb_b, 196608);
  cast_bf16_k<<<cgrid(393216),  256, 0, stream>>>(whhf_f, whhf_b, 393216);
  cast_bf16_k<<<cgrid(393216),  256, 0, stream>>>(whhb_f, whhb_b, 393216);
  cast_bf16_k<<<cgrid(1179648), 256, 0, stream>>>(wihd,   wihd_b, 1179648);
  cast_bf16_k<<<cgrid(393216),  256, 0, stream>>>(whhd_f, whhd_b, 393216);
  cast_bf16_k<<<cgrid(393216),  256, 0, stream>>>(w1,     w1_b,   393216);
  cast_bf16_k<<<cgrid(4096000), 256, 0, stream>>>(outw,   outw_b, 4096000);

  gemm_bt<0,0><<<dim3(24,16), 256, 0, stream>>>(x_b, 512, wihf_b,      512,  bihf,    gi_f, 3072, 512);
  gemm_bt<0,0><<<dim3(24,16), 256, 0, stream>>>(x_b, 512, wihb_b,      512,  bihb,    gi_b, 3072, 512);
  gemm_bt<0,0><<<dim3(24,16), 256, 0, stream>>>(x_b, 512, wihd_b,      3072, bihd,    gi_d, 3072, 512);
  gemm_bt<0,1><<<dim3(24,16), 256, 0, stream>>>(lo_b,512, wihd_b+2560, 3072, nullptr, gi_d, 3072, 512);

  enc_init_k<<<32, 256, 0, stream>>>(einit, henc_b, hfE);
  for (int s = 0; s < 64; ++s){
    const bf16* hrd = henc_b + (size_t)(s&1)*65536;
    bf16*       hwr = henc_b + (size_t)((s+1)&1)*65536;
    enc_step_k<<<64, 256, 0, stream>>>(gi_f, gi_b, whhf_b, whhb_b, bhhf, bhhb,
                                       hrd, hwr, hfE, enc_b, s);
  }

  gemm_bt<1,0><<<dim3(8,16),  256, 0, stream>>>(enc_b, 2048, w1_b,       3072, nullptr, encW1_b, 1024, 2048);
  gemm_bt<1,0><<<dim3(24,16), 256, 0, stream>>>(enc_b, 2048, wihd_b+512, 3072, nullptr, encWg_b, 3072, 2048);

  dec_init_k<<<16, 256, 0, stream>>>(dinh, hdb, hfD);
  for (int t = 0; t < 64; ++t){
    const bf16* hdr = hdb + (size_t)(t&1)*32768;
    bf16*       hdw = hdb + (size_t)((t+1)&1)*32768;
    dec_k1<<<64, 256, 0, stream>>>(hdr, whhd_b, bhhd, w1_b, ghb, hW1b);
    dec_k2<<<64, 256, 0, stream>>>(encW1_b, hW1b, w2, wat);
    dec_k3<<<128, 256, 0, stream>>>(gi_d + (size_t)t*B_*H3_, encWg_b, ghb, wat,
                                    hfD, hdw, hall_b + (size_t)t*B_*H_);
  }

  gemm_bt<0,0><<<dim3(250,16), 256, 0, stream>>>(hall_b, 1024, outw_b, 1024, outb, out, 32000, 1024);
  softmax_rows_k<<<2048, 256, 0, stream>>>(out);
}